// Round 1
// 82562.640 us; speedup vs baseline: 2.3252x; 2.3252x over previous
//
#include <hip/hip_runtime.h>
#include <hip/hip_bf16.h>

typedef __hip_bfloat16 bf16;
typedef unsigned long long u64;

#define NSTEP 1024
#define BATCH 64
#define HID   512
#define GRID  256
#define NTHR  256
#define KC    64      // k-chunk per ks-half staged per iteration

// ---- workspace layout (bytes) ----
// bar counter @0 (RMW line), release word @128 (poll line), flag @64
#define OFF_BAR   0u
#define OFF_FLAG  64u
#define OFF_HG    256u
#define OFF_CG    131328u
#define OFF_GALL  262400u
#define OFF_UCAT  2883840u
#define OFF_WA    23855360u
#define OFF_WM    24903936u
#define OFF_WX    25166080u
#define OFF_BM    25362688u
#define OFF_BX    25370880u
#define OFF_BA    25403648u
#define OFF_YT    25405696u
#define OFF_XT    33794304u

// ---- LDS carve (float indices), total 36864 floats = 144 KB ----
#define L_US    0
#define L_WML   20640
#define L_HA    22080
#define L_YA    30528
#define L_XA    32640
#define L_RED   34176
#define L_LB    30528
#define L_MP    35208
#define L_TOT   36864

#define US(c,k)    smem[L_US  + (c)*516 + (k)]
#define WML(c,j)   smem[L_WML + (c)*36  + (j)]
#define HA(s,b,k)  smem[L_HA  + (s)*4224 + (b)*66 + (k)]
#define YA(b,j)    smem[L_YA  + (b)*33 + (j)]
#define XA(a,b,j)  smem[L_XA  + ((a)*64 + (b))*3 + (j)]
#define RED(q,j)   smem[L_RED + (q)*21 + (j)]
#define LB(j,h)    smem[L_LB  + (j)*520 + (h)]
#define MP(q,j)    smem[L_MP  + (q)*12 + (j)]

struct RawIn {
  const void *Y, *x[8];
  const void *W_i,*U_i,*b_i, *W_f,*U_f,*b_f, *W_c,*U_c,*b_c, *W_o,*U_o,*b_o;
  const void *W_ix,*U_ix,*b_ix, *W_cx,*U_cx,*b_cx, *W_a,*b_a;
  float *Ucat,*Wa,*Wm,*Wx,*Bm,*Bx,*Ba,*Yt,*Xt;
  const unsigned *flag;
};

struct Params {
  const float *Ucat,*Wa,*Wm,*Wx,*Bm,*Bx,*Ba,*Yt,*Xt;
  float *Hg,*Cg,*Gall;
  unsigned *bar;
  const unsigned *flag;
  void *out;
};

// ---------------- dtype probe -------------------------------------------------
__global__ void k_detect(const unsigned short* __restrict__ p, unsigned* flag) {
  if (blockIdx.x == 0 && threadIdx.x == 0) {
    int cnt = 0;
    for (int i = 0; i < 64; ++i) {
      unsigned e = (p[i] >> 7) & 0xFF;
      cnt += (e >= 0x60 && e <= 0x7C) || (p[i] & 0x7FFF) == 0;
    }
    *flag = (cnt >= 56) ? 1u : 0u;   // 1 = bf16, 0 = fp32
  }
}

__device__ __forceinline__ float cvt(const void* p, size_t i, bool bf) {
  return bf ? (float)((const bf16*)p)[i] : ((const float*)p)[i];
}

// ---------------- weight normalization ---------------------------------------
#define NWTOT 5605888
__global__ __launch_bounds__(256)
void k_conv_w(RawIn R) {
  const bool bf = (*R.flag) != 0;
  for (size_t i = blockIdx.x*256 + threadIdx.x; i < NWTOT; i += (size_t)gridDim.x*256) {
    if (i < 5242880) {           // Ucat [20][512][512]
      size_t g = i >> 18, r = i & 262143;
      const void* s = g<4 ? (g==0?R.U_i:g==1?R.U_f:g==2?R.U_c:R.U_o)
                    : g<12 ? R.U_ix : R.U_cx;
      size_t off = g<4 ? r : g<12 ? (g-4)*262144 + r : (g-12)*262144 + r;
      R.Ucat[i] = cvt(s, off, bf);
    } else {
      size_t j = i - 5242880;
      if (j < 262144) { R.Wa[j] = cvt(R.W_a, j, bf); }
      else {
        size_t j2 = j - 262144;
        if (j2 < 65536) {        // Wm [4][32][512]
          size_t g = j2 >> 14, r = j2 & 16383;
          const void* s = g==0?R.W_i:g==1?R.W_f:g==2?R.W_c:R.W_o;
          R.Wm[j2] = cvt(s, r, bf);
        } else {
          size_t j3 = j2 - 65536;
          if (j3 < 24576) {      // Wx [16][3][512]
            size_t p = j3 / 1536, r = j3 % 1536;
            R.Wx[j3] = p < 8 ? cvt(R.W_ix, p*1536 + r, bf)
                             : cvt(R.W_cx, (p-8)*1536 + r, bf);
          } else {
            size_t j4 = j3 - 24576;
            if (j4 < 2048) {     // Bm [4][512]
              size_t g = j4 >> 9, c = j4 & 511;
              const void* s = g==0?R.b_i:g==1?R.b_f:g==2?R.b_c:R.b_o;
              R.Bm[j4] = cvt(s, c, bf);
            } else {
              size_t j5 = j4 - 2048;
              if (j5 < 8192) {   // Bx [16][512]
                size_t p = j5 >> 9, c = j5 & 511;
                R.Bx[j5] = p < 8 ? cvt(R.b_ix, p*512 + c, bf)
                                 : cvt(R.b_cx, (p-8)*512 + c, bf);
              } else {
                size_t j6 = j5 - 8192;       // Ba [512]
                R.Ba[j6] = cvt(R.b_a, j6, bf);
              }
            }
          }
        }
      }
    }
  }
}

// ---------------- input normalization (time-major pack) -----------------------
#define NYT 2097152
#define NXT 1572864
__global__ __launch_bounds__(256)
void k_conv_in(RawIn R) {
  const bool bf = (*R.flag) != 0;
  for (size_t i = blockIdx.x*256 + threadIdx.x; i < NYT+NXT; i += (size_t)gridDim.x*256) {
    if (i < NYT) {               // Yt [t][b][32]
      size_t j = i & 31, b = (i >> 5) & 63, t = i >> 11;
      R.Yt[i] = cvt(R.Y, (b*32 + j)*NSTEP + t, bf);
    } else {                     // Xt [t][8][b][3]
      size_t i2 = i - NYT;
      size_t j = i2 % 3, r = i2 / 3;
      size_t b = r & 63; r >>= 6;
      size_t a = r & 7, t = r >> 3;
      R.Xt[i2] = cvt(R.x[a], (b*3 + j)*NSTEP + t, bf);
    }
  }
}

// ---------------- helpers -----------------------------------------------------

__device__ __forceinline__ float sigf(float v){ return 1.f/(1.f+expf(-v)); }

__device__ __forceinline__ float gload(const float* p){
  return __hip_atomic_load(p, __ATOMIC_RELAXED, __HIP_MEMORY_SCOPE_AGENT);
}
__device__ __forceinline__ u64 gload2(const float* p){
  return __hip_atomic_load((const u64*)p, __ATOMIC_RELAXED, __HIP_MEMORY_SCOPE_AGENT);
}
__device__ __forceinline__ void gstore(float* p, float v){
  __hip_atomic_store(p, v, __ATOMIC_RELAXED, __HIP_MEMORY_SCOPE_AGENT);
}

// Fence-free grid barrier.
// All cross-WG data moves through sc1 (agent-scope relaxed atomic) ops that
// bypass the non-coherent XCD L2s, so NO __threadfence (= buffer_wbl2 +
// buffer_inv, which flushed+invalidated L2 2048x per run) is needed.
// Ordering: s_waitcnt vmcnt(0) (drained by __syncthreads) ensures prior sc1
// stores reached the coherence point before the counter RMW.
// Protocol: everyone RMWs the counter line (byte 0); WG0 alone polls it and
// publishes epoch to the release word (byte 128, separate line); others poll
// the read-only release line -> no 256-way read storm on the RMW line.
__device__ __forceinline__ void gbar(unsigned* bar, unsigned bi) {
  asm volatile("s_waitcnt vmcnt(0)" ::: "memory");
  __syncthreads();
  if (threadIdx.x == 0) {
    __hip_atomic_fetch_add(bar, 1u, __ATOMIC_RELAXED, __HIP_MEMORY_SCOPE_AGENT);
    unsigned* rel = bar + 32;   // byte offset 128
    if (blockIdx.x == 0) {
      while (__hip_atomic_load(bar, __ATOMIC_RELAXED, __HIP_MEMORY_SCOPE_AGENT) < bi*GRID)
        __builtin_amdgcn_s_sleep(1);
      __hip_atomic_store(rel, bi, __ATOMIC_RELAXED, __HIP_MEMORY_SCOPE_AGENT);
    } else {
      while (__hip_atomic_load(rel, __ATOMIC_RELAXED, __HIP_MEMORY_SCOPE_AGENT) < bi)
        __builtin_amdgcn_s_sleep(4);
    }
  }
  __syncthreads();
}

// ---------------- persistent kernel (grid == #CUs) ----------------------------

__global__ __launch_bounds__(NTHR)
void lstm_main(Params P) {
  extern __shared__ float smem[];

  const bool bfout = (*P.flag) != 0;

  const int w   = blockIdx.x;
  const int tid = threadIdx.x;
  // phase A: WG owns 40 unique columns, all 64 rows.
  const int c0  = w * 40;
  const int cgr = tid & 7;          // 8 col groups x 5 cols
  const int rgr = (tid >> 3) & 15;  // 16 row groups; rows rgr + 16*i
  const int ksl = tid >> 7;         // k-split half (0: k<256, 1: k>=256)
  const int cl  = cgr * 5;
  // phase B mapping: 64 b x 4 h'-quarters
  const int pb  = w >> 2;
  const int ph0 = (w & 3) * 128;
  const int hl  = tid >> 1;
  const int kh  = tid & 1;
  const int hp  = ph0 + hl;

  // ---- one-time init: U strip + per-column input-proj weights into LDS ----
  for (int e = tid; e < 40*512; e += NTHR) {
    int c = e >> 9, k = e & 511;
    int cg = c0 + c, g = cg >> 9, cc = cg & 511;
    US(c, k) = P.Ucat[((size_t)g*HID + k)*HID + cc];
  }
  for (int e = tid; e < 40*33; e += NTHR) {
    int c = e / 33, jj = e % 33;
    int cg = c0 + c, g = cg >> 9, cc = cg & 511;
    float v;
    if (jj == 32) {            // bias slot
      v = g < 4  ? P.Bm[g*HID + cc]
        : g < 12 ? P.Bx[(g-4)*HID + cc]
                 : P.Bx[(8 + g-12)*HID + cc];
    } else if (g < 4) {
      v = P.Wm[((size_t)g*32 + jj)*HID + cc];
    } else if (jj < 3) {
      int p = (g < 12) ? (g-4) : (8 + g-12);
      v = P.Wx[((size_t)p*3 + jj)*HID + cc];
    } else v = 0.f;
    WML(c, jj) = v;
  }
  __syncthreads();

  unsigned bi = 0;

  // prefetch registers for Hg staging (16 x 8B per thread = one 64-k chunk)
  u64 pre[16];
  auto hgld = [&](int kcc) {
#pragma unroll
    for (int u = 0; u < 16; ++u) {
      int e2 = tid + u*NTHR;
      int s2 = e2 >> 11, b = (e2 >> 5) & 63, k = (e2 & 31) * 2;
      pre[u] = gload2(&P.Hg[(size_t)b*HID + s2*256 + kcc + k]);
    }
  };

  for (int t = 0; t < NSTEP; ++t) {
    // ===== phase A: z[64][40] = h @ Us (+input proj) -> Gall =====
    for (int e = tid; e < 64*32; e += NTHR) {
      int b = e >> 5, j = e & 31;
      YA(b, j) = P.Yt[((size_t)t*BATCH + b)*32 + j];
    }
    for (int e = tid; e < 8*64*3; e += NTHR) {
      int j2 = e % 3; int r = e / 3; int b = r & 63; int a = r >> 6;
      XA(a, b, j2) = P.Xt[(((size_t)t*8 + a)*BATCH + b)*3 + j2];
    }

    hgld(0);   // issue chunk-0 loads; land under first LDS writes

    float acc[4][5];
#pragma unroll
    for (int i=0;i<4;++i)
#pragma unroll
      for (int j=0;j<5;++j) acc[i][j]=0.f;

    for (int kc = 0; kc < 256; kc += KC) {
      __syncthreads();                       // prev chunk's HA reads done
#pragma unroll
      for (int u = 0; u < 16; ++u) {         // regs -> LDS
        int e2 = tid + u*NTHR;
        int s2 = e2 >> 11, b = (e2 >> 5) & 63, k = (e2 & 31) * 2;
        union { u64 u_; float f[2]; } v; v.u_ = pre[u];
        float2 t2; t2.x = v.f[0]; t2.y = v.f[1];
        *(float2*)&HA(s2, b, k) = t2;
      }
      __syncthreads();
      if (kc + KC < 256) hgld(kc + KC);      // next chunk in flight over compute

      const int kb = ksl*256 + kc;
#pragma unroll 4
      for (int kk = 0; kk < KC; kk += 2) {
        float2 h0 = *(const float2*)&HA(ksl, rgr,      kk);
        float2 h1 = *(const float2*)&HA(ksl, rgr+16,   kk);
        float2 h2 = *(const float2*)&HA(ksl, rgr+32,   kk);
        float2 h3 = *(const float2*)&HA(ksl, rgr+48,   kk);
#pragma unroll
        for (int j = 0; j < 5; ++j) {
          float2 u = *(const float2*)&US(cl+j, kb+kk);
          acc[0][j] += h0.x*u.x; acc[0][j] += h0.y*u.y;
          acc[1][j] += h1.x*u.x; acc[1][j] += h1.y*u.y;
          acc[2][j] += h2.x*u.x; acc[2][j] += h2.y*u.y;
          acc[3][j] += h3.x*u.x; acc[3][j] += h3.y*u.y;
        }
      }
    }

    // k-split reduction: ks=1 threads hand partials to ks=0 partner
    if (ksl) {
      int q = tid - 128;
#pragma unroll
      for (int i=0;i<4;++i)
#pragma unroll
        for (int j=0;j<5;++j) RED(q, i*5+j) = acc[i][j];
    }
    __syncthreads();
    if (!ksl) {
#pragma unroll
      for (int i=0;i<4;++i)
#pragma unroll
        for (int j=0;j<5;++j) acc[i][j] += RED(tid, i*5+j);

      // epilogue: input projection + bias + nonlinearity -> Gall
#pragma unroll
      for (int i = 0; i < 4; ++i) {
        int row = rgr + 16*i;
#pragma unroll
        for (int j = 0; j < 5; ++j) {
          int c = cl + j, cg = c0 + c, g = cg >> 9, cc = cg & 511;
          float v = acc[i][j];
          float s = WML(c, 32);
          if (g < 4) {
            for (int jj = 0; jj < 32; ++jj)
              s += YA(row, jj) * WML(c, jj);
            v += s;
            v = (g==2) ? tanhf(v) : sigf(v);
          } else if (g < 12) {
            int p = g-4; int a = (p==0) ? 0 : 1;  // ref quirk: i_x 2..8 all read x2
            for (int jj = 0; jj < 3; ++jj)
              s += XA(a, row, jj) * WML(c, jj);
            v = sigf(v + s);
          } else {
            int p = g-12;
            for (int jj = 0; jj < 3; ++jj)
              s += XA(p, row, jj) * WML(c, jj);
            v = tanhf(v + s);
          }
          gstore(&P.Gall[((size_t)g*BATCH + row)*HID + cc], v);
        }
      }
    }

    gbar(P.bar, ++bi);

    // ===== phase B: m = l_all @ W_a, softmax mix, state update =====
    for (int e = tid; e < 9*256; e += NTHR) {   // 8B-wide Gall staging
      int j = e >> 8, h2 = (e & 255) << 1;
      union { u64 u_; float f[2]; } a, b2;
      if (j == 0) {
        a.u_  = gload2(&P.Gall[((size_t)0*BATCH+pb)*HID+h2]);
        b2.u_ = gload2(&P.Gall[((size_t)2*BATCH+pb)*HID+h2]);
      } else {
        int p = j-1;
        a.u_  = gload2(&P.Gall[((size_t)(4+p)*BATCH+pb)*HID+h2]);
        b2.u_ = gload2(&P.Gall[((size_t)(12+p)*BATCH+pb)*HID+h2]);
      }
      float2 t2; t2.x = a.f[0]*b2.f[0]; t2.y = a.f[1]*b2.f[1];
      *(float2*)&LB(j, h2) = t2;
    }
    __syncthreads();

    float a9[9];
#pragma unroll
    for (int j=0;j<9;++j) a9[j]=0.f;
    {
      const int k0 = kh*256;
      const float* wa = P.Wa + (size_t)k0*HID + hp;
#pragma unroll 2
      for (int k = 0; k < 256; k += 4) {
        float w0 = wa[(size_t)(k+0)*HID];
        float w1 = wa[(size_t)(k+1)*HID];
        float w2 = wa[(size_t)(k+2)*HID];
        float w3 = wa[(size_t)(k+3)*HID];
#pragma unroll
        for (int j=0;j<9;++j) {
          float4 l4 = *(const float4*)&LB(j, k0+k);
          a9[j] += l4.x*w0; a9[j] += l4.y*w1; a9[j] += l4.z*w2; a9[j] += l4.w*w3;
        }
      }
    }
    if (kh) {
#pragma unroll
      for (int j=0;j<9;++j) MP(hl, j) = a9[j];
    }
    __syncthreads();
    if (!kh) {
      float co = P.Cg[(size_t)pb*HID + hp];
      float ba = P.Ba[hp];
      float u9[9], mx = -1e30f;
#pragma unroll
      for (int j=0;j<9;++j) {
        float m = a9[j] + MP(hl, j);
        u9[j] = tanhf(m*co + ba);
        mx = fmaxf(mx, u9[j]);
      }
      float ssum = 0.f, L = 0.f;
#pragma unroll
      for (int j=0;j<9;++j) {
        float e2 = expf(u9[j]-mx);
        ssum += e2;
        L += e2 * LB(j, hp);
      }
      L /= ssum;
      float f = gload(&P.Gall[((size_t)1*BATCH+pb)*HID + hp]);
      float o = gload(&P.Gall[((size_t)3*BATCH+pb)*HID + hp]);
      float cn = f*co + L;
      float hn = o*tanhf(cn);
      P.Cg[(size_t)pb*HID + hp] = cn;
      gstore(&P.Hg[(size_t)pb*HID + hp], hn);
      size_t iseq = (size_t)BATCH*HID + ((size_t)pb*NSTEP + t)*HID + hp;
      if (bfout) ((bf16*)P.out)[iseq] = __float2bfloat16(hn);
      else       ((float*)P.out)[iseq] = hn;
      if (t == NSTEP-1) {
        size_t ih = (size_t)pb*HID + hp;
        if (bfout) ((bf16*)P.out)[ih] = __float2bfloat16(hn);
        else       ((float*)P.out)[ih] = hn;
      }
    }

    gbar(P.bar, ++bi);
  }
}

// ---------------- host entry --------------------------------------------------

extern "C" void kernel_launch(void* const* d_in, const int* in_sizes, int n_in,
                              void* d_out, int out_size, void* d_ws, size_t ws_size,
                              hipStream_t stream) {
  char* ws = (char*)d_ws;

  RawIn R;
  R.Y = d_in[0];
  for (int i = 0; i < 8; ++i) R.x[i] = d_in[1+i];
  R.W_i=d_in[9];  R.U_i=d_in[10]; R.b_i=d_in[11];
  R.W_f=d_in[12]; R.U_f=d_in[13]; R.b_f=d_in[14];
  R.W_c=d_in[15]; R.U_c=d_in[16]; R.b_c=d_in[17];
  R.W_o=d_in[18]; R.U_o=d_in[19]; R.b_o=d_in[20];
  R.W_ix=d_in[21]; R.U_ix=d_in[22]; R.b_ix=d_in[23];
  R.W_cx=d_in[24]; R.U_cx=d_in[25]; R.b_cx=d_in[26];
  R.W_a =d_in[27]; R.b_a =d_in[28];
  R.Ucat=(float*)(ws+OFF_UCAT); R.Wa=(float*)(ws+OFF_WA);
  R.Wm=(float*)(ws+OFF_WM); R.Wx=(float*)(ws+OFF_WX);
  R.Bm=(float*)(ws+OFF_BM); R.Bx=(float*)(ws+OFF_BX); R.Ba=(float*)(ws+OFF_BA);
  R.Yt=(float*)(ws+OFF_YT); R.Xt=(float*)(ws+OFF_XT);
  R.flag=(const unsigned*)(ws+OFF_FLAG);

  Params P;
  P.Ucat=R.Ucat; P.Wa=R.Wa; P.Wm=R.Wm; P.Wx=R.Wx;
  P.Bm=R.Bm; P.Bx=R.Bx; P.Ba=R.Ba; P.Yt=R.Yt; P.Xt=R.Xt;
  P.Hg=(float*)(ws+OFF_HG); P.Cg=(float*)(ws+OFF_CG); P.Gall=(float*)(ws+OFF_GALL);
  P.bar=(unsigned*)(ws+OFF_BAR);
  P.flag=R.flag;
  P.out=d_out;

  // zero barrier/release/flag + Hg + Cg (ws is poisoned 0xAA before every call)
  hipMemsetAsync(d_ws, 0, OFF_GALL, stream);

  k_detect<<<1, 64, 0, stream>>>((const unsigned short*)d_in[10], (unsigned*)(ws+OFF_FLAG));
  k_conv_w <<<21899, 256, 0, stream>>>(R);
  k_conv_in<<<14336, 256, 0, stream>>>(R);

  const int smemBytes = L_TOT * 4;   // 147456 B = 144 KB (<160 KB/CU, 1 WG/CU)
  hipFuncSetAttribute((const void*)lstm_main,
                      hipFuncAttributeMaxDynamicSharedMemorySize, smemBytes);
  lstm_main<<<dim3(GRID), dim3(NTHR), smemBytes, stream>>>(P);
}

// Round 2
// 61554.419 us; speedup vs baseline: 3.1188x; 1.3413x over previous
//
#include <hip/hip_runtime.h>
#include <hip/hip_bf16.h>

typedef __hip_bfloat16 bf16;
typedef unsigned long long u64;

#define NSTEP 1024
#define BATCH 64
#define HID   512
#define GRID  256
#define NTHR  512
#define KC    64      // k-chunk per ks-half staged per iteration

// ---- workspace layout (bytes) ----
// bar counter @0 (RMW line), release word @128 (poll line), flag @64
#define OFF_BAR   0u
#define OFF_FLAG  64u
#define OFF_HG    256u
#define OFF_CG    131328u
#define OFF_GALL  262400u
#define OFF_UCAT  2883840u
#define OFF_WA    23855360u
#define OFF_WM    24903936u
#define OFF_WX    25166080u
#define OFF_BM    25362688u
#define OFF_BX    25370880u
#define OFF_BA    25403648u
#define OFF_YT    25405696u
#define OFF_XT    33794304u

// ---- LDS carve (float indices) ----
// persistent: US[40][524], WML[40][36], HA[2][64][68]
// overlay A : YA[64][33], XA[8][64][3], RED[256][11]  (+GB[64][40] @ LB base)
// overlay B : LB[9][520], MP[128][27]
#define L_US    0
#define L_WML   20960
#define L_HA    22400
#define L_YA    31104
#define L_XA    33216
#define L_RED   34752
#define L_GB    31104     /* overlays LB zone; barrier-separated from YA use */
#define L_LB    31104
#define L_MP    35784
#define L_TOT   39240     /* 156960 B < 160 KB */

#define US(c,k)    smem[L_US  + (c)*524 + (k)]
#define WML(c,j)   smem[L_WML + (c)*36  + (j)]
#define HA(s,b,k)  smem[L_HA  + (s)*4352 + (b)*68 + (k)]
#define YA(b,j)    smem[L_YA  + (b)*33 + (j)]
#define XA(a,b,j)  smem[L_XA  + ((a)*64 + (b))*3 + (j)]
#define RED(q,j)   smem[L_RED + (q)*11 + (j)]
#define GB(r,c)    smem[L_GB  + (r)*40 + (c)]
#define LB(j,h)    smem[L_LB  + (j)*520 + (h)]
#define MP(q,j)    smem[L_MP  + (q)*27 + (j)]

struct RawIn {
  const void *Y, *x[8];
  const void *W_i,*U_i,*b_i, *W_f,*U_f,*b_f, *W_c,*U_c,*b_c, *W_o,*U_o,*b_o;
  const void *W_ix,*U_ix,*b_ix, *W_cx,*U_cx,*b_cx, *W_a,*b_a;
  float *Ucat,*Wa,*Wm,*Wx,*Bm,*Bx,*Ba,*Yt,*Xt;
  const unsigned *flag;
};

struct Params {
  const float *Ucat,*Wa,*Wm,*Wx,*Bm,*Bx,*Ba,*Yt,*Xt;
  float *Hg,*Cg,*Gall;
  unsigned *bar;
  const unsigned *flag;
  void *out;
};

// ---------------- dtype probe -------------------------------------------------
__global__ void k_detect(const unsigned short* __restrict__ p, unsigned* flag) {
  if (blockIdx.x == 0 && threadIdx.x == 0) {
    int cnt = 0;
    for (int i = 0; i < 64; ++i) {
      unsigned e = (p[i] >> 7) & 0xFF;
      cnt += (e >= 0x60 && e <= 0x7C) || (p[i] & 0x7FFF) == 0;
    }
    *flag = (cnt >= 56) ? 1u : 0u;   // 1 = bf16, 0 = fp32
  }
}

__device__ __forceinline__ float cvt(const void* p, size_t i, bool bf) {
  return bf ? (float)((const bf16*)p)[i] : ((const float*)p)[i];
}

// ---------------- weight normalization ---------------------------------------
#define NWTOT 5605888
__global__ __launch_bounds__(256)
void k_conv_w(RawIn R) {
  const bool bf = (*R.flag) != 0;
  for (size_t i = blockIdx.x*256 + threadIdx.x; i < NWTOT; i += (size_t)gridDim.x*256) {
    if (i < 5242880) {           // Ucat [20][512][512]
      size_t g = i >> 18, r = i & 262143;
      const void* s = g<4 ? (g==0?R.U_i:g==1?R.U_f:g==2?R.U_c:R.U_o)
                    : g<12 ? R.U_ix : R.U_cx;
      size_t off = g<4 ? r : g<12 ? (g-4)*262144 + r : (g-12)*262144 + r;
      R.Ucat[i] = cvt(s, off, bf);
    } else {
      size_t j = i - 5242880;
      if (j < 262144) { R.Wa[j] = cvt(R.W_a, j, bf); }
      else {
        size_t j2 = j - 262144;
        if (j2 < 65536) {        // Wm [4][32][512]
          size_t g = j2 >> 14, r = j2 & 16383;
          const void* s = g==0?R.W_i:g==1?R.W_f:g==2?R.W_c:R.W_o;
          R.Wm[j2] = cvt(s, r, bf);
        } else {
          size_t j3 = j2 - 65536;
          if (j3 < 24576) {      // Wx [16][3][512]
            size_t p = j3 / 1536, r = j3 % 1536;
            R.Wx[j3] = p < 8 ? cvt(R.W_ix, p*1536 + r, bf)
                             : cvt(R.W_cx, (p-8)*1536 + r, bf);
          } else {
            size_t j4 = j3 - 24576;
            if (j4 < 2048) {     // Bm [4][512]
              size_t g = j4 >> 9, c = j4 & 511;
              const void* s = g==0?R.b_i:g==1?R.b_f:g==2?R.b_c:R.b_o;
              R.Bm[j4] = cvt(s, c, bf);
            } else {
              size_t j5 = j4 - 2048;
              if (j5 < 8192) {   // Bx [16][512]
                size_t p = j5 >> 9, c = j5 & 511;
                R.Bx[j5] = p < 8 ? cvt(R.b_ix, p*512 + c, bf)
                                 : cvt(R.b_cx, (p-8)*512 + c, bf);
              } else {
                size_t j6 = j5 - 8192;       // Ba [512]
                R.Ba[j6] = cvt(R.b_a, j6, bf);
              }
            }
          }
        }
      }
    }
  }
}

// ---------------- input normalization (time-major pack) -----------------------
#define NYT 2097152
#define NXT 1572864
__global__ __launch_bounds__(256)
void k_conv_in(RawIn R) {
  const bool bf = (*R.flag) != 0;
  for (size_t i = blockIdx.x*256 + threadIdx.x; i < NYT+NXT; i += (size_t)gridDim.x*256) {
    if (i < NYT) {               // Yt [t][b][32]
      size_t j = i & 31, b = (i >> 5) & 63, t = i >> 11;
      R.Yt[i] = cvt(R.Y, (b*32 + j)*NSTEP + t, bf);
    } else {                     // Xt [t][8][b][3]
      size_t i2 = i - NYT;
      size_t j = i2 % 3, r = i2 / 3;
      size_t b = r & 63; r >>= 6;
      size_t a = r & 7, t = r >> 3;
      R.Xt[i2] = cvt(R.x[a], (b*3 + j)*NSTEP + t, bf);
    }
  }
}

// ---------------- helpers -----------------------------------------------------

__device__ __forceinline__ float sigf(float v){ return 1.f/(1.f+expf(-v)); }

__device__ __forceinline__ float gload(const float* p){
  return __hip_atomic_load(p, __ATOMIC_RELAXED, __HIP_MEMORY_SCOPE_AGENT);
}
__device__ __forceinline__ u64 gload2(const float* p){
  return __hip_atomic_load((const u64*)p, __ATOMIC_RELAXED, __HIP_MEMORY_SCOPE_AGENT);
}
__device__ __forceinline__ void gstore(float* p, float v){
  __hip_atomic_store(p, v, __ATOMIC_RELAXED, __HIP_MEMORY_SCOPE_AGENT);
}
__device__ __forceinline__ void gstore2(float* p, float x, float y){
  union { u64 u_; float f[2]; } v; v.f[0]=x; v.f[1]=y;
  __hip_atomic_store((u64*)p, v.u_, __ATOMIC_RELAXED, __HIP_MEMORY_SCOPE_AGENT);
}

// Fence-free grid barrier (see R1 notes): all cross-WG data moves through sc1
// agent-scope relaxed atomics which bypass the non-coherent XCD L2s, so no
// __threadfence (L2 flush) is needed. s_waitcnt vmcnt(0) + s_barrier orders
// prior sc1 stores before the counter RMW. WG0 polls the RMW line and
// publishes to a separate release line that everyone else polls read-only.
__device__ __forceinline__ void gbar(unsigned* bar, unsigned bi) {
  asm volatile("s_waitcnt vmcnt(0)" ::: "memory");
  __syncthreads();
  if (threadIdx.x == 0) {
    __hip_atomic_fetch_add(bar, 1u, __ATOMIC_RELAXED, __HIP_MEMORY_SCOPE_AGENT);
    unsigned* rel = bar + 32;   // byte offset 128
    if (blockIdx.x == 0) {
      while (__hip_atomic_load(bar, __ATOMIC_RELAXED, __HIP_MEMORY_SCOPE_AGENT) < bi*GRID)
        __builtin_amdgcn_s_sleep(1);
      __hip_atomic_store(rel, bi, __ATOMIC_RELAXED, __HIP_MEMORY_SCOPE_AGENT);
    } else {
      while (__hip_atomic_load(rel, __ATOMIC_RELAXED, __HIP_MEMORY_SCOPE_AGENT) < bi)
        __builtin_amdgcn_s_sleep(2);
    }
  }
  __syncthreads();
}

// ---------------- persistent kernel (grid == #CUs, 512 thr = 8 waves/CU) ------

__global__ __launch_bounds__(NTHR)
void lstm_main(Params P) {
  extern __shared__ float smem[];

  const bool bfout = (*P.flag) != 0;

  const int w   = blockIdx.x;
  const int tid = threadIdx.x;
  // phase A: WG owns 40 unique columns, all 64 rows.
  const int c0  = w * 40;
  const int cgr = tid & 7;          // 8 col groups x 5 cols
  const int rgr = (tid >> 3) & 31;  // 32 row groups; rows rgr, rgr+32
  const int ksl = tid >> 8;         // k-split half (0: k<256, 1: k>=256)
  const int cl  = cgr * 5;
  // phase B mapping: batch pb, 128 h-cols; wave-contiguous hl, 4-way k-split
  const int pb  = w >> 2;
  const int ph0 = (w & 3) * 128;
  const int hl  = tid & 127;        // consecutive within a wave -> coalesced Wa
  const int kq  = tid >> 7;         // k-quarter 0..3
  const int hp  = ph0 + hl;

  // ---- one-time init: U strip + per-column input-proj weights into LDS ----
  for (int e = tid; e < 40*512; e += NTHR) {
    int c = e >> 9, k = e & 511;
    int cg = c0 + c, g = cg >> 9, cc = cg & 511;
    US(c, k) = P.Ucat[((size_t)g*HID + k)*HID + cc];
  }
  for (int e = tid; e < 40*33; e += NTHR) {
    int c = e / 33, jj = e % 33;
    int cg = c0 + c, g = cg >> 9, cc = cg & 511;
    float v;
    if (jj == 32) {            // bias slot
      v = g < 4  ? P.Bm[g*HID + cc]
        : g < 12 ? P.Bx[(g-4)*HID + cc]
                 : P.Bx[(8 + g-12)*HID + cc];
    } else if (g < 4) {
      v = P.Wm[((size_t)g*32 + jj)*HID + cc];
    } else if (jj < 3) {
      int p = (g < 12) ? (g-4) : (8 + g-12);
      v = P.Wx[((size_t)p*3 + jj)*HID + cc];
    } else v = 0.f;
    WML(c, jj) = v;
  }
  __syncthreads();

  unsigned bi = 0;

  // prefetch registers for Hg staging (8 x 8B per thread = one 64-k chunk)
  u64 pre[8];
  auto hgld = [&](int kcc) {
#pragma unroll
    for (int u = 0; u < 8; ++u) {
      int e2 = tid + u*NTHR;
      int s2 = e2 >> 11, b = (e2 >> 5) & 63, k = (e2 & 31) * 2;
      pre[u] = gload2(&P.Hg[(size_t)b*HID + s2*256 + kcc + k]);
    }
  };

  for (int t = 0; t < NSTEP; ++t) {
    // ===== phase A: z[64][40] = h @ Us (+input proj) -> Gall =====
    for (int e = tid; e < 64*32; e += NTHR) {
      int b = e >> 5, j = e & 31;
      YA(b, j) = P.Yt[((size_t)t*BATCH + b)*32 + j];
    }
    for (int e = tid; e < 8*64*3; e += NTHR) {
      int j2 = e % 3; int r = e / 3; int b = r & 63; int a = r >> 6;
      XA(a, b, j2) = P.Xt[(((size_t)t*8 + a)*BATCH + b)*3 + j2];
    }

    hgld(0);   // issue chunk-0 loads; land under LDS writes

    float acc[2][5];
#pragma unroll
    for (int i=0;i<2;++i)
#pragma unroll
      for (int j=0;j<5;++j) acc[i][j]=0.f;

    for (int kc = 0; kc < 256; kc += KC) {
      __syncthreads();                       // prev chunk's HA reads done
#pragma unroll
      for (int u = 0; u < 8; ++u) {          // regs -> LDS
        int e2 = tid + u*NTHR;
        int s2 = e2 >> 11, b = (e2 >> 5) & 63, k = (e2 & 31) * 2;
        union { u64 u_; float f[2]; } v; v.u_ = pre[u];
        float2 t2; t2.x = v.f[0]; t2.y = v.f[1];
        *(float2*)&HA(s2, b, k) = t2;
      }
      __syncthreads();
      if (kc + KC < 256) hgld(kc + KC);      // next chunk in flight over compute

      const int kb = ksl*256 + kc;
#pragma unroll 4
      for (int kk = 0; kk < KC; kk += 4) {
        float4 h0 = *(const float4*)&HA(ksl, rgr,      kk);
        float4 h1 = *(const float4*)&HA(ksl, rgr+32,   kk);
#pragma unroll
        for (int j = 0; j < 5; ++j) {
          float4 u = *(const float4*)&US(cl+j, kb+kk);
          acc[0][j] += h0.x*u.x; acc[0][j] += h0.y*u.y;
          acc[0][j] += h0.z*u.z; acc[0][j] += h0.w*u.w;
          acc[1][j] += h1.x*u.x; acc[1][j] += h1.y*u.y;
          acc[1][j] += h1.z*u.z; acc[1][j] += h1.w*u.w;
        }
      }
    }

    // k-split reduction: ksl=1 threads hand partials to ksl=0 partner
    if (ksl) {
      int q = tid - 256;
#pragma unroll
      for (int i=0;i<2;++i)
#pragma unroll
        for (int j=0;j<5;++j) RED(q, i*5+j) = acc[i][j];
    }
    __syncthreads();

    float vv[2][5];
    if (!ksl) {
      // epilogue: input projection + bias + nonlinearity (into registers)
#pragma unroll
      for (int i = 0; i < 2; ++i) {
        int row = rgr + 32*i;
#pragma unroll
        for (int j = 0; j < 5; ++j) {
          int c = cl + j, cg = c0 + c, g = cg >> 9;
          float v = acc[i][j] + RED(tid, i*5+j);
          float s = WML(c, 32);
          if (g < 4) {
            for (int jj = 0; jj < 32; ++jj)
              s += YA(row, jj) * WML(c, jj);
            v += s;
            v = (g==2) ? tanhf(v) : sigf(v);
          } else if (g < 12) {
            int p = g-4; int a = (p==0) ? 0 : 1;  // ref quirk: i_x 2..8 all read x2
            for (int jj = 0; jj < 3; ++jj)
              s += XA(a, row, jj) * WML(c, jj);
            v = sigf(v + s);
          } else {
            int p = g-12;
            for (int jj = 0; jj < 3; ++jj)
              s += XA(p, row, jj) * WML(c, jj);
            v = tanhf(v + s);
          }
          vv[i][j] = v;
        }
      }
    }
    __syncthreads();               // YA/XA reads done before GB overwrites them
    if (!ksl) {
#pragma unroll
      for (int i = 0; i < 2; ++i)
#pragma unroll
        for (int j = 0; j < 5; ++j)
          GB(rgr + 32*i, cl + j) = vv[i][j];
    }
    __syncthreads();
    // cooperative coalesced Gall store: float2, pair never straddles a gate
    for (int e = tid; e < 64*20; e += NTHR) {
      int row = e / 20, p = e % 20;
      int cc2 = c0 + 2*p;
      int g = cc2 >> 9, cc = cc2 & 511;
      gstore2(&P.Gall[((size_t)g*BATCH + row)*HID + cc], GB(row, 2*p), GB(row, 2*p+1));
    }

    gbar(P.bar, ++bi);

    // ===== phase B: m = l_all @ W_a, softmax mix, state update =====
    for (int e = tid; e < 9*256; e += NTHR) {   // 8B-wide Gall staging
      int j = e >> 8, h2 = (e & 255) << 1;
      union { u64 u_; float f[2]; } a, b2;
      if (j == 0) {
        a.u_  = gload2(&P.Gall[((size_t)0*BATCH+pb)*HID+h2]);
        b2.u_ = gload2(&P.Gall[((size_t)2*BATCH+pb)*HID+h2]);
      } else {
        int p = j-1;
        a.u_  = gload2(&P.Gall[((size_t)(4+p)*BATCH+pb)*HID+h2]);
        b2.u_ = gload2(&P.Gall[((size_t)(12+p)*BATCH+pb)*HID+h2]);
      }
      float2 t2; t2.x = a.f[0]*b2.f[0]; t2.y = a.f[1]*b2.f[1];
      *(float2*)&LB(j, h2) = t2;
    }
    __syncthreads();

    float a9[9];
#pragma unroll
    for (int j=0;j<9;++j) a9[j]=0.f;
    {
      const int k0 = kq * 128;
      const float* wa = P.Wa + (size_t)k0*HID + hp;
#pragma unroll 2
      for (int k = 0; k < 128; k += 4) {
        float w0 = wa[(size_t)(k+0)*HID];
        float w1 = wa[(size_t)(k+1)*HID];
        float w2 = wa[(size_t)(k+2)*HID];
        float w3 = wa[(size_t)(k+3)*HID];
#pragma unroll
        for (int j=0;j<9;++j) {
          float4 l4 = *(const float4*)&LB(j, k0+k);
          a9[j] += l4.x*w0; a9[j] += l4.y*w1; a9[j] += l4.z*w2; a9[j] += l4.w*w3;
        }
      }
    }
    if (kq) {
#pragma unroll
      for (int j=0;j<9;++j) MP(hl, (kq-1)*9 + j) = a9[j];
    }
    __syncthreads();
    if (!kq) {
      float co = P.Cg[(size_t)pb*HID + hp];
      float ba = P.Ba[hp];
      float u9[9], mx = -1e30f;
#pragma unroll
      for (int j=0;j<9;++j) {
        float m = a9[j] + MP(hl, j) + MP(hl, 9+j) + MP(hl, 18+j);
        u9[j] = tanhf(m*co + ba);
        mx = fmaxf(mx, u9[j]);
      }
      float ssum = 0.f, L = 0.f;
#pragma unroll
      for (int j=0;j<9;++j) {
        float e2 = expf(u9[j]-mx);
        ssum += e2;
        L += e2 * LB(j, hp);
      }
      L /= ssum;
      float f = gload(&P.Gall[((size_t)1*BATCH+pb)*HID + hp]);
      float o = gload(&P.Gall[((size_t)3*BATCH+pb)*HID + hp]);
      float cn = f*co + L;
      float hn = o*tanhf(cn);
      P.Cg[(size_t)pb*HID + hp] = cn;
      gstore(&P.Hg[(size_t)pb*HID + hp], hn);
      size_t iseq = (size_t)BATCH*HID + ((size_t)pb*NSTEP + t)*HID + hp;
      if (bfout) ((bf16*)P.out)[iseq] = __float2bfloat16(hn);
      else       ((float*)P.out)[iseq] = hn;
      if (t == NSTEP-1) {
        size_t ih = (size_t)pb*HID + hp;
        if (bfout) ((bf16*)P.out)[ih] = __float2bfloat16(hn);
        else       ((float*)P.out)[ih] = hn;
      }
    }

    gbar(P.bar, ++bi);
  }
}

// ---------------- host entry --------------------------------------------------

extern "C" void kernel_launch(void* const* d_in, const int* in_sizes, int n_in,
                              void* d_out, int out_size, void* d_ws, size_t ws_size,
                              hipStream_t stream) {
  char* ws = (char*)d_ws;

  RawIn R;
  R.Y = d_in[0];
  for (int i = 0; i < 8; ++i) R.x[i] = d_in[1+i];
  R.W_i=d_in[9];  R.U_i=d_in[10]; R.b_i=d_in[11];
  R.W_f=d_in[12]; R.U_f=d_in[13]; R.b_f=d_in[14];
  R.W_c=d_in[15]; R.U_c=d_in[16]; R.b_c=d_in[17];
  R.W_o=d_in[18]; R.U_o=d_in[19]; R.b_o=d_in[20];
  R.W_ix=d_in[21]; R.U_ix=d_in[22]; R.b_ix=d_in[23];
  R.W_cx=d_in[24]; R.U_cx=d_in[25]; R.b_cx=d_in[26];
  R.W_a =d_in[27]; R.b_a =d_in[28];
  R.Ucat=(float*)(ws+OFF_UCAT); R.Wa=(float*)(ws+OFF_WA);
  R.Wm=(float*)(ws+OFF_WM); R.Wx=(float*)(ws+OFF_WX);
  R.Bm=(float*)(ws+OFF_BM); R.Bx=(float*)(ws+OFF_BX); R.Ba=(float*)(ws+OFF_BA);
  R.Yt=(float*)(ws+OFF_YT); R.Xt=(float*)(ws+OFF_XT);
  R.flag=(const unsigned*)(ws+OFF_FLAG);

  Params P;
  P.Ucat=R.Ucat; P.Wa=R.Wa; P.Wm=R.Wm; P.Wx=R.Wx;
  P.Bm=R.Bm; P.Bx=R.Bx; P.Ba=R.Ba; P.Yt=R.Yt; P.Xt=R.Xt;
  P.Hg=(float*)(ws+OFF_HG); P.Cg=(float*)(ws+OFF_CG); P.Gall=(float*)(ws+OFF_GALL);
  P.bar=(unsigned*)(ws+OFF_BAR);
  P.flag=R.flag;
  P.out=d_out;

  // zero barrier/release/flag + Hg + Cg (ws is poisoned 0xAA before every call)
  hipMemsetAsync(d_ws, 0, OFF_GALL, stream);

  k_detect<<<1, 64, 0, stream>>>((const unsigned short*)d_in[10], (unsigned*)(ws+OFF_FLAG));
  k_conv_w <<<21899, 256, 0, stream>>>(R);
  k_conv_in<<<14336, 256, 0, stream>>>(R);

  const int smemBytes = L_TOT * 4;   // 156960 B < 160 KB/CU -> 1 WG/CU, 8 waves
  hipFuncSetAttribute((const void*)lstm_main,
                      hipFuncAttributeMaxDynamicSharedMemorySize, smemBytes);
  lstm_main<<<dim3(GRID), dim3(NTHR), smemBytes, stream>>>(P);
}